// Round 1
// baseline (194.758 us; speedup 1.0000x reference)
//
#include <hip/hip_runtime.h>

#define NN  1024
#define HH  64
#define DYF 0.0009765625f   // 1/1024

// tanh(x) = 1 - 2/(exp(2x)+1); safe at +/-inf (exp->inf => 1, exp->0 => -1)
__device__ __forceinline__ float tfast(float x) {
  float e = __expf(2.0f * x);
  return 1.0f - __fdividef(2.0f, e + 1.0f);
}

// out[i] = hom[i] + Hb2 + b3 * (sum_j f[j]) * DY
__global__ __launch_bounds__(1024) void init_kernel(
    const float* __restrict__ f, const float* __restrict__ ys,
    const float* __restrict__ b3,
    const float* __restrict__ Hw1, const float* __restrict__ Hb1,
    const float* __restrict__ Hw2, const float* __restrict__ Hb2,
    float* __restrict__ out)
{
  __shared__ float red[NN];
  int t = threadIdx.x;
  red[t] = f[t];
  __syncthreads();
  for (int s = NN / 2; s > 0; s >>= 1) {
    if (t < s) red[t] += red[t + s];
    __syncthreads();
  }
  float G = red[0];
  float y = ys[t];
  float hom = 0.0f;
  #pragma unroll
  for (int l = 0; l < HH; ++l)
    hom += Hw2[l] * tfast(fmaf(y, Hw1[l], Hb1[l]));
  out[t] = hom + Hb2[0] + b3[0] * G * DYF;
}

// Block: 256 threads = 16 i's x 16 j-lanes; each thread does (i, j) and (i, j+16).
// Grid: (1024/16, 1024/32) = (64, 32).
__global__ __launch_bounds__(256) void main_kernel(
    const float* __restrict__ f, const float* __restrict__ ys,
    const float* __restrict__ W1, const float* __restrict__ b1,
    const float* __restrict__ W2, const float* __restrict__ b2,
    const float* __restrict__ W3,
    float* __restrict__ out)
{
  __shared__ float4 sW2[HH * 16];     // [m][lg] quads over l, 16 KB
  __shared__ float  sw1a[HH], sw1b[HH], sb1[HH];
  __shared__ float4 sb2[16], sW3[16];
  __shared__ float  sred[256];

  const int t = threadIdx.x;

  const float4* gW2 = (const float4*)W2;
  for (int k = t; k < HH * 16; k += 256) sW2[k] = gW2[k];
  if (t < HH) { sw1a[t] = W1[t]; sw1b[t] = W1[HH + t]; sb1[t] = b1[t]; }
  if (t < 16) { sb2[t] = ((const float4*)b2)[t]; sW3[t] = ((const float4*)W3)[t]; }
  __syncthreads();

  const int i  = blockIdx.x * 16 + (t >> 4);
  const int j  = blockIdx.y * 32 + (t & 15);
  const float yi  = ys[i];
  const float yja = ys[j];
  const float yjb = ys[j + 16];

  // Layer 1: h1[m] = tanh(yi*W1[0][m] + yj*W1[1][m] + b1[m]); fully unrolled -> registers
  float h1a[HH], h1b[HH];
  #pragma unroll
  for (int m = 0; m < HH; ++m) {
    float base = fmaf(yi, sw1a[m], sb1[m]);
    h1a[m] = tfast(fmaf(yja, sw1b[m], base));
    h1b[m] = tfast(fmaf(yjb, sw1b[m], base));
  }

  // Layer 2 (64x64) + layer 3 dot, 4 output channels at a time
  float ka = 0.0f, kb = 0.0f;
  #pragma unroll 1
  for (int lg = 0; lg < 16; ++lg) {
    float4 bq = sb2[lg];
    float a0 = bq.x, a1 = bq.y, a2 = bq.z, a3 = bq.w;
    float c0 = bq.x, c1 = bq.y, c2 = bq.z, c3 = bq.w;
    #pragma unroll
    for (int m = 0; m < HH; ++m) {
      float4 w = sW2[m * 16 + lg];   // wave-uniform address -> LDS broadcast
      float xa = h1a[m], xb = h1b[m];
      a0 = fmaf(w.x, xa, a0); a1 = fmaf(w.y, xa, a1);
      a2 = fmaf(w.z, xa, a2); a3 = fmaf(w.w, xa, a3);
      c0 = fmaf(w.x, xb, c0); c1 = fmaf(w.y, xb, c1);
      c2 = fmaf(w.z, xb, c2); c3 = fmaf(w.w, xb, c3);
    }
    float4 w3 = sW3[lg];
    ka += w3.x * tfast(a0) + w3.y * tfast(a1) + w3.z * tfast(a2) + w3.w * tfast(a3);
    kb += w3.x * tfast(c0) + w3.y * tfast(c1) + w3.z * tfast(c2) + w3.w * tfast(c3);
  }

  // weight by g_j = f[j]*DY and reduce 16 j-lanes per i
  float su = f[j] * DYF * ka + f[j + 16] * DYF * kb;
  sred[t] = su;
  __syncthreads();
  if (t < 16) {
    float s = 0.0f;
    #pragma unroll
    for (int q = 0; q < 16; ++q) s += sred[t * 16 + q];
    atomicAdd(&out[blockIdx.x * 16 + t], s);
  }
}

extern "C" void kernel_launch(void* const* d_in, const int* in_sizes, int n_in,
                              void* d_out, int out_size, void* d_ws, size_t ws_size,
                              hipStream_t stream) {
  const float* f   = (const float*)d_in[0];
  const float* ys  = (const float*)d_in[1];
  const float* W1  = (const float*)d_in[2];
  const float* b1  = (const float*)d_in[3];
  const float* W2  = (const float*)d_in[4];
  const float* b2  = (const float*)d_in[5];
  const float* W3  = (const float*)d_in[6];
  const float* b3  = (const float*)d_in[7];
  const float* Hw1 = (const float*)d_in[8];
  const float* Hb1 = (const float*)d_in[9];
  const float* Hw2 = (const float*)d_in[10];
  const float* Hb2 = (const float*)d_in[11];
  float* out = (float*)d_out;

  init_kernel<<<1, NN, 0, stream>>>(f, ys, b3, Hw1, Hb1, Hw2, Hb2, out);
  main_kernel<<<dim3(NN / 16, NN / 32), 256, 0, stream>>>(f, ys, W1, b1, W2, b2, W3, out);
}

// Round 2
// 58.820 us; speedup vs baseline: 3.3111x; 3.3111x over previous
//
#include <hip/hip_runtime.h>
#include <hip/hip_bf16.h>

#define NN  1024
#define HH  64
#define DYF 0.0009765625f            // 1/1024
#define SCL 2.8853900817779268f      // 2*log2(e): tanh(x) = 1 - 2/(2^(SCL*x)+1)

typedef __attribute__((ext_vector_type(4)))  float f32x4;
typedef __attribute__((ext_vector_type(16))) float f32x16;
typedef __attribute__((ext_vector_type(8)))  short bf16x8s;

// tanh via hw exp: safe at +/-inf
__device__ __forceinline__ float tfast(float x) {
  float e = __expf(2.0f * x);
  return 1.0f - __fdividef(2.0f, e + 1.0f);
}

// ---------------- hom kernel: out[i] = hom[i] + Hb2 + b3 * (sum f) * DY ----
__global__ __launch_bounds__(1024) void hom_kernel(
    const float* __restrict__ f, const float* __restrict__ ys,
    const float* __restrict__ b3,
    const float* __restrict__ Hw1, const float* __restrict__ Hb1,
    const float* __restrict__ Hw2, const float* __restrict__ Hb2,
    float* __restrict__ out)
{
  __shared__ float red[NN];
  int t = threadIdx.x;
  red[t] = f[t];
  __syncthreads();
  for (int s = NN / 2; s > 0; s >>= 1) {
    if (t < s) red[t] += red[t + s];
    __syncthreads();
  }
  float G = red[0];
  float y = ys[t];
  float hom = 0.0f;
  #pragma unroll
  for (int l = 0; l < HH; ++l)
    hom += Hw2[l] * tfast(fmaf(y, Hw1[l], Hb1[l]));
  out[t] = hom + Hb2[0] + b3[0] * G * DYF;
}

// ---------------- prep: A'[i][m]=SCL*yi*W1[0][m]; C'[j][m]=SCL*(yj*W1[1][m]+b1[m]);
//                  W2f = bf16(SCL*W2) pre-swizzled into B-fragment order -------
__global__ __launch_bounds__(256) void prep_kernel(
    const float* __restrict__ ys, const float* __restrict__ W1,
    const float* __restrict__ b1, const float* __restrict__ W2,
    float* __restrict__ Ap, float* __restrict__ Cp, ushort* __restrict__ W2f)
{
  int gt = blockIdx.x * 256 + threadIdx.x;      // 0..16383
  int row = gt >> 4, part = gt & 15;
  float y = ys[row];
  #pragma unroll
  for (int q = 0; q < 4; ++q) {
    int m = part * 4 + q;
    Ap[row * HH + m] = SCL * y * W1[m];                       // W1[0][m]
    Cp[row * HH + m] = SCL * fmaf(y, W1[HH + m], b1[m]);      // W1[1][m]
  }
  if (gt < 4096) {
    // flat = (((tile*4+ks)*2+h)*32 + c)*8 + e ; value = SCL*W2[ks*16+h*8+e][tile*32+c]
    int e = gt & 7, c = (gt >> 3) & 31, h = (gt >> 8) & 1, ks = (gt >> 9) & 3, tl = gt >> 11;
    int k = ks * 16 + h * 8 + e;
    float v = SCL * W2[k * HH + tl * 32 + c];
    __hip_bfloat16 hb = __float2bfloat16(v);
    W2f[gt] = *reinterpret_cast<ushort*>(&hb);
  }
}

// ---------------- main: wave = 32 i's x all-channel MFMA, loop over 16 j's ----
#define JC 16

__global__ __launch_bounds__(256, 2) void main_kernel(
    const float* __restrict__ f, const float* __restrict__ b2,
    const float* __restrict__ W3,
    const float* __restrict__ Ap, const float* __restrict__ Cp,
    const ushort* __restrict__ W2f, float* __restrict__ out)
{
  const int l    = threadIdx.x & 63;
  const int W    = blockIdx.x * 4 + (threadIdx.x >> 6);
  const int ib   = (W & 31) * 32;          // i-tile base
  const int j0   = (W >> 5) * JC;          // j-slice base
  const int half = l >> 5;
  const int c    = l & 31;
  const int b4   = half * 2;               // float4 offset of this lane's k-slice

  // W2 B-fragments (held in regs for whole kernel)
  const bf16x8s* w2v = (const bf16x8s*)W2f;
  bf16x8s B0[4], B1[4];
  #pragma unroll
  for (int ks = 0; ks < 4; ++ks) {
    B0[ks] = w2v[((0 * 4 + ks) * 2 + half) * 32 + c];
    B1[ks] = w2v[((1 * 4 + ks) * 2 + half) * 32 + c];
  }

  // a' for this lane's row (i = ib + c), its 32 k-channels
  const f32x4* arow = (const f32x4*)(Ap + (size_t)(ib + c) * HH);
  f32x4 A[8];
  #pragma unroll
  for (int ks = 0; ks < 4; ++ks) {
    A[ks * 2]     = arow[ks * 4 + b4];
    A[ks * 2 + 1] = arow[ks * 4 + b4 + 1];
  }

  const float b2s0 = SCL * b2[c],       b2s1 = SCL * b2[32 + c];
  const float w3d0 = W3[c] * DYF,       w3d1 = W3[32 + c] * DYF;

  f32x16 u{};   // per-row u accumulators (summed over j and this lane's channels)

#define LOADC(CR, jj) do {                                                  \
    const f32x4* crow = (const f32x4*)(Cp + (size_t)(jj) * HH);             \
    CR[0] = crow[b4];      CR[1] = crow[b4 + 1];                            \
    CR[2] = crow[4 + b4];  CR[3] = crow[4 + b4 + 1];                        \
    CR[4] = crow[8 + b4];  CR[5] = crow[8 + b4 + 1];                        \
    CR[6] = crow[12 + b4]; CR[7] = crow[12 + b4 + 1];                       \
  } while (0)

#define COMPUTE(CR, jj) do {                                                \
    float fj = f[jj];                                                       \
    float wg0 = w3d0 * fj, wg1 = w3d1 * fj;                                 \
    f32x16 acc0{}, acc1{};                                                  \
    _Pragma("unroll")                                                       \
    for (int ks = 0; ks < 4; ++ks) {                                        \
      float t[8];                                                           \
      _Pragma("unroll")                                                     \
      for (int q = 0; q < 2; ++q) {                                         \
        f32x4 z = A[ks * 2 + q] + CR[ks * 2 + q];                           \
        _Pragma("unroll")                                                   \
        for (int e = 0; e < 4; ++e) {                                       \
          float ez = __builtin_amdgcn_exp2f(z[e]);                          \
          float rr = __builtin_amdgcn_rcpf(ez + 1.0f);                      \
          t[q * 4 + e] = fmaf(-2.0f, rr, 1.0f);                             \
        }                                                                   \
      }                                                                     \
      union { bf16x8s s; __hip_bfloat162 h[4]; } fr;                        \
      fr.h[0] = __float22bfloat162_rn(make_float2(t[0], t[1]));             \
      fr.h[1] = __float22bfloat162_rn(make_float2(t[2], t[3]));             \
      fr.h[2] = __float22bfloat162_rn(make_float2(t[4], t[5]));             \
      fr.h[3] = __float22bfloat162_rn(make_float2(t[6], t[7]));             \
      acc0 = __builtin_amdgcn_mfma_f32_32x32x16_bf16(fr.s, B0[ks], acc0, 0, 0, 0); \
      acc1 = __builtin_amdgcn_mfma_f32_32x32x16_bf16(fr.s, B1[ks], acc1, 0, 0, 0); \
    }                                                                       \
    _Pragma("unroll")                                                       \
    for (int r = 0; r < 16; ++r) {                                          \
      float e0 = __builtin_amdgcn_exp2f(acc0[r] + b2s0);                    \
      float r0 = __builtin_amdgcn_rcpf(e0 + 1.0f);                          \
      float t0 = fmaf(-2.0f, r0, 1.0f);                                     \
      float e1 = __builtin_amdgcn_exp2f(acc1[r] + b2s1);                    \
      float r1 = __builtin_amdgcn_rcpf(e1 + 1.0f);                          \
      float t1 = fmaf(-2.0f, r1, 1.0f);                                     \
      u[r] = fmaf(t0, wg0, fmaf(t1, wg1, u[r]));                            \
    }                                                                       \
  } while (0)

  f32x4 CA[8], CB[8];
  LOADC(CA, j0);
  #pragma unroll 1
  for (int jj = 0; jj < JC; jj += 2) {
    LOADC(CB, j0 + jj + 1);
    COMPUTE(CA, j0 + jj);
    if (jj + 2 < JC) LOADC(CA, j0 + jj + 2);
    COMPUTE(CB, j0 + jj + 1);
  }

  // reduce this lane's channel-partials across the 32 lanes of its half
  #pragma unroll
  for (int r = 0; r < 16; ++r) {
    float v = u[r];
    v += __shfl_xor(v, 1);
    v += __shfl_xor(v, 2);
    v += __shfl_xor(v, 4);
    v += __shfl_xor(v, 8);
    v += __shfl_xor(v, 16);
    if (c == 0) {
      int row = (r & 3) + 8 * (r >> 2) + 4 * half;
      atomicAdd(&out[ib + row], v);
    }
  }
#undef LOADC
#undef COMPUTE
}

extern "C" void kernel_launch(void* const* d_in, const int* in_sizes, int n_in,
                              void* d_out, int out_size, void* d_ws, size_t ws_size,
                              hipStream_t stream) {
  const float* f   = (const float*)d_in[0];
  const float* ys  = (const float*)d_in[1];
  const float* W1  = (const float*)d_in[2];
  const float* b1  = (const float*)d_in[3];
  const float* W2  = (const float*)d_in[4];
  const float* b2  = (const float*)d_in[5];
  const float* W3  = (const float*)d_in[6];
  const float* b3  = (const float*)d_in[7];
  const float* Hw1 = (const float*)d_in[8];
  const float* Hb1 = (const float*)d_in[9];
  const float* Hw2 = (const float*)d_in[10];
  const float* Hb2 = (const float*)d_in[11];
  float* out = (float*)d_out;

  float*  Ap  = (float*)d_ws;                    // 1024*64 f32
  float*  Cp  = Ap + NN * HH;                    // 1024*64 f32
  ushort* W2f = (ushort*)(Cp + NN * HH);         // 4096 bf16 (8 KB)

  hom_kernel<<<1, NN, 0, stream>>>(f, ys, b3, Hw1, Hb1, Hw2, Hb2, out);
  prep_kernel<<<64, 256, 0, stream>>>(ys, W1, b1, W2, Ap, Cp, W2f);
  // 2048 waves: 32 i-tiles x 64 j-slices of JC=16
  main_kernel<<<512, 256, 0, stream>>>(f, b2, W3, Ap, Cp, W2f, out);
}